// Round 5
// baseline (1771.249 us; speedup 1.0000x reference)
//
#include <hip/hip_runtime.h>

// ---- static config (mirrors reference) ----
#define BB   2
#define NN   8192
#define KNN  40
#define SENT 8192
#define G0   17          // ceil coords for dl=0.06, pts in [0,1)
#define G1   9           // for dl=0.12
#define G0_3 (G0*G0*G0)  // 4913
#define G1_3 (G1*G1*G1)  // 729

#define QB    64         // queries per chunk (one per lane)
#define QCH   (NN/64)    // 128 query chunks per batch
#define SPLIT 8          // support-split factor
#define NWAVE 8          // waves per block (fallback single-kernel path)
#define BQT   512        // threads per block (fallback path)

typedef unsigned long long ull;
typedef unsigned int       u32;
typedef unsigned short     u16;

// d2 exactly as numpy: (dx*dx + dy*dy) + dz*dz, no FMA contraction
__device__ __forceinline__ float sqdist(float qx, float qy, float qz,
                                        float sx, float sy, float sz) {
    float dx = __fsub_rn(qx, sx);
    float dy = __fsub_rn(qy, sy);
    float dz = __fsub_rn(qz, sz);
    return __fadd_rn(__fadd_rn(__fmul_rn(dx, dx), __fmul_rn(dy, dy)),
                     __fmul_rn(dz, dz));
}

// prep: copy pts -> out_points[0], fill layer-2 pool/up with SENTINEL, len[0]
__global__ void prep_kernel(const float* __restrict__ pts, float* __restrict__ dout) {
    const size_t PN = (size_t)BB * NN * 3;
    const size_t IN = (size_t)BB * NN * KNN;
    float* out_points0 = dout;
    float* out_pool2   = dout + 3 * PN + 3 * IN + 2 * IN;
    float* out_up2     = dout + 3 * PN + 6 * IN + 2 * IN;
    float* out_len     = dout + 3 * PN + 9 * IN;
    int i = blockIdx.x * 256 + threadIdx.x;
    if (i < (int)PN) out_points0[i] = pts[i];
    if (i < (int)IN) {
        out_pool2[i] = (float)SENT;
        out_up2[i]   = (float)SENT;
    }
    if (i == 0) { out_len[0] = (float)NN; out_len[1] = (float)NN; }
}

// ---- 40 named register slots for the sorted top-40 key list ----
#define FORALL_K(M) \
    M(0,k00) M(1,k01) M(2,k02) M(3,k03) M(4,k04) M(5,k05) M(6,k06) M(7,k07) \
    M(8,k08) M(9,k09) M(10,k10) M(11,k11) M(12,k12) M(13,k13) M(14,k14) M(15,k15) \
    M(16,k16) M(17,k17) M(18,k18) M(19,k19) M(20,k20) M(21,k21) M(22,k22) M(23,k23) \
    M(24,k24) M(25,k25) M(26,k26) M(27,k27) M(28,k28) M(29,k29) M(30,k30) M(31,k31) \
    M(32,k32) M(33,k33) M(34,k34) M(35,k35) M(36,k36) M(37,k37) M(38,k38) M(39,k39)

// Key = (f32_bits(d2) << 13) | idx  (d2 >= 0 so float bits are order-monotone;
// idx < 8192 fits 13 bits).  u64 key compare == (d2, idx) lexicographic order,
// exactly the reference's stable top_k tie-break (lower idx first).
// Empty slot = all-ones key (INITK); merge maps it to SENT.
// Selection of the 40 smallest keys is candidate-ORDER-INDEPENDENT, so the
// support partition across waves is semantics-free.

// The scan + insertion body, shared textually by both bq variants.
//   in:  qx,qy,qz, r2, sp, j0, j1   out: k00..k39 updated
#define BQ_SCAN_BODY                                                              \
    for (int base = j0; base < j1; base += 64) {                                  \
        int nj = min(64, j1 - base);                                              \
        float px = 0.f, py = 0.f, pz = 0.f;                                       \
        {                                                                         \
            int jj = base + lane;                                                 \
            if (lane < nj) {                                                      \
                px = sp[jj * 3];                                                  \
                py = sp[jj * 3 + 1];                                              \
                pz = sp[jj * 3 + 2];                                              \
            }                                                                     \
        }                                                                         \
        _Pragma("unroll 1")                                                       \
        for (int u = 0; u < nj; ++u) {                                            \
            float sx = __shfl(px, u);                                             \
            float sy = __shfl(py, u);                                             \
            float sz = __shfl(pz, u);                                             \
            float d2 = sqdist(qx, qy, qz, sx, sy, sz);                            \
            if (d2 <= r2) {                                                       \
                ull ck = (((ull)__float_as_uint(d2)) << 13) | (ull)(u32)(base + u);\
                if (ck < k39) {                                                   \
                    SW1(k00) SW1(k01) SW1(k02) SW1(k03) SW1(k04) SW1(k05) SW1(k06) SW1(k07) \
                    if (__any(ck != INITK)) {                                     \
                        SW1(k08) SW1(k09) SW1(k10) SW1(k11) SW1(k12) SW1(k13) SW1(k14) SW1(k15) \
                        if (__any(ck != INITK)) {                                 \
                            SW1(k16) SW1(k17) SW1(k18) SW1(k19) SW1(k20) SW1(k21) SW1(k22) SW1(k23) \
                            if (__any(ck != INITK)) {                             \
                                SW1(k24) SW1(k25) SW1(k26) SW1(k27) SW1(k28) SW1(k29) SW1(k30) SW1(k31) \
                                if (__any(ck != INITK)) {                         \
                                    SW1(k32) SW1(k33) SW1(k34) SW1(k35) SW1(k36) SW1(k37) SW1(k38) SW1(k39) \
                                }                                                 \
                            }                                                     \
                        }                                                         \
                    }                                                             \
                }                                                                 \
            }                                                                     \
        }                                                                         \
    }

#define SW1(K) { bool sw_ = ck < K; ull t_ = sw_ ? K : ck; K = sw_ ? ck : K; ck = t_; }

// ---- PASS 1: independent-wave partial top-40 -> global workspace ----
// 4 independent waves per 256-thread block: NO LDS, NO barriers, no block
// tail coupling (R4 post-mortem: OccupancyPercent ~2% with 2048 resident
// waves => dispatch time was a straggler-BLOCK tail of the 120KiB-LDS
// monolithic kernel, not inner-loop cost).
// wave id gw -> (b, qc, split); dumps 40 (u32 d2bits, u16 idx) rows,
// lane-major (coalesced 256B/128B row stores).
__global__ __launch_bounds__(256) void bq_part(
    const float* __restrict__ qpts, const float* __restrict__ spts,
    const int* __restrict__ qlen_ptr, int qlen_const,
    const int* __restrict__ slen_ptr, int slen_const,
    u32* __restrict__ wsH, u16* __restrict__ wsL, float r2) {
    const ull INITK = ~0ull;
    int t = threadIdx.x;
    int lane = t & 63;
    int gw = blockIdx.x * 4 + (t >> 6);       // 0 .. BB*QCH*SPLIT-1
    int b = gw >> 10;                         // QCH*SPLIT = 1024 waves/batch
    int rem = gw & 1023;
    int qc = rem >> 3;
    int split = rem & 7;
    int qlen = qlen_ptr ? qlen_ptr[b] : qlen_const;
    int slen = slen_ptr ? slen_ptr[b] : slen_const;
    if (qc * QB >= qlen) return;              // wave-uniform; merge writes SENT

#define DECL_K(I,K) ull K = INITK;
    FORALL_K(DECL_K)
#undef DECL_K

    {
        int qi = qc * QB + lane;
        const float* qp = qpts + ((size_t)b * NN + qi) * 3;
        float qx = qp[0], qy = qp[1], qz = qp[2];
        if (qi >= qlen) { qx = 1.0e30f; qy = 1.0e30f; qz = 1.0e30f; } // d2=inf -> never accepts
        int j0 = (slen * split) >> 3;
        int j1 = (slen * (split + 1)) >> 3;
        const float* sp = spts + (size_t)b * NN * 3;
        BQ_SCAN_BODY
    }
    // dump: entry e = ((rowq + k)*SPLIT + split)*64 + lane
    size_t rowq = ((size_t)b * QCH + qc) * KNN;
#define DUMP_K(I,K) { size_t e_ = ((rowq + I) * SPLIT + split) * 64 + lane;  \
                      wsH[e_] = (u32)(K >> 13); wsL[e_] = (u16)(K & 0x1FFFu); }
    FORALL_K(DUMP_K)
#undef DUMP_K
}

// ---- PASS 2: stable 8-way merge by key, 1 thread per query ----
// Identical comparator / pointer updates / SENT logic as the in-LDS merge
// -> bit-identical output.  Pointers sum to k <= 39 -> p[c] <= 39, no OOB.
__global__ __launch_bounds__(256) void bq_merge(
    const u32* __restrict__ wsH, const u16* __restrict__ wsL,
    const int* __restrict__ qlen_ptr, int qlen_const,
    float* __restrict__ out) {
    int b = blockIdx.y;
    int qi = blockIdx.x * 256 + threadIdx.x;
    int qc = qi >> 6;
    int lane = qi & 63;
    int qlen = qlen_ptr ? qlen_ptr[b] : qlen_const;
    float* op = out + ((size_t)b * NN + qi) * KNN;
    if (qc * QB >= qlen) {                    // chunk never dumped -> all SENT
        for (int k = 0; k < KNN; ++k) op[k] = (float)SENT;
        return;
    }
    size_t rowq = ((size_t)b * QCH + qc) * KNN;
    int p[SPLIT];
#pragma unroll
    for (int c = 0; c < SPLIT; ++c) p[c] = 0;
    for (int k = 0; k < KNN; ++k) {
        ull bk = ~0ull; int bw = 0;
#pragma unroll
        for (int c = 0; c < SPLIT; ++c) {
            size_t e = ((rowq + p[c]) * SPLIT + c) * 64 + lane;
            ull kk = (((ull)wsH[e]) << 13) | (ull)wsL[e];
            if (kk < bk) { bk = kk; bw = c; }  // reconstructed keys < 2^45-1 == INIT
        }
#pragma unroll
        for (int c = 0; c < SPLIT; ++c) p[c] += (bw == c);
        op[k] = ((u32)(bk >> 13) == 0xFFFFFFFFu) ? (float)SENT
                                                 : (float)(int)(bk & 0x1FFFu);
    }
}

// ---- fallback single-kernel path (proven; used only if ws too small) ----
__global__ __launch_bounds__(BQT, 2) void bq_kernel(
    const float* __restrict__ qpts, const float* __restrict__ spts,
    const int* __restrict__ qlen_ptr, int qlen_const,
    const int* __restrict__ slen_ptr, int slen_const,
    float* __restrict__ out, float r2) {
    __shared__ u32 khl[NWAVE][KNN][QB];
    __shared__ u16 kll[NWAVE][KNN][QB];
    const ull INITK = ~0ull;
    int t = threadIdx.x;
    int w = __builtin_amdgcn_readfirstlane(t >> 6);
    int lane = t & 63;
    int b = blockIdx.y;
    int qbase = blockIdx.x * QB;
    int qi = qbase + lane;
    int qlen = qlen_ptr ? qlen_ptr[b] : qlen_const;
    int slen = slen_ptr ? slen_ptr[b] : slen_const;
#define DECL_K(I,K) ull K = INITK;
    FORALL_K(DECL_K)
#undef DECL_K
    if (qbase < qlen) {
        const float* qp = qpts + ((size_t)b * NN + qi) * 3;
        float qx = qp[0], qy = qp[1], qz = qp[2];
        if (qi >= qlen) { qx = 1.0e30f; qy = 1.0e30f; qz = 1.0e30f; }
        int j0 = (slen * w) >> 3;
        int j1 = (slen * (w + 1)) >> 3;
        const float* sp = spts + (size_t)b * NN * 3;
        BQ_SCAN_BODY
    }
#define DUMP_K(I,K) khl[w][I][lane] = (u32)(K >> 13); kll[w][I][lane] = (u16)(K & 0x1FFFu);
    FORALL_K(DUMP_K)
#undef DUMP_K
    __syncthreads();
    if (w == 0) {
        float* op = out + ((size_t)b * NN + qi) * KNN;
        int p[NWAVE];
#pragma unroll
        for (int c = 0; c < NWAVE; ++c) p[c] = 0;
        for (int k = 0; k < KNN; ++k) {
            ull bk = ~0ull; int bw = 0;
#pragma unroll
            for (int c = 0; c < NWAVE; ++c) {
                ull kk = (((ull)khl[c][p[c]][lane]) << 13) | (ull)kll[c][p[c]][lane];
                if (kk < bk) { bk = kk; bw = c; }
            }
#pragma unroll
            for (int c = 0; c < NWAVE; ++c) p[c] += (bw == c);
            op[k] = ((u32)(bk >> 13) == 0xFFFFFFFFu) ? (float)SENT
                                                     : (float)(int)(bk & 0x1FFFu);
        }
    }
}

// per-point voxel id (f32 division, f32 dl)
__global__ void vid_kernel(const float* __restrict__ pts,
                           const int* __restrict__ len_ptr, int len_const,
                           int* __restrict__ vid, float dlf, int G) {
    int b = blockIdx.y;
    int i = blockIdx.x * 256 + threadIdx.x;
    int len = len_ptr ? len_ptr[b] : len_const;
    if (i >= len) return;
    const float* p = pts + ((size_t)b * NN + i) * 3;
    int cx = (int)floorf(__fdiv_rn(p[0], dlf));
    int cy = (int)floorf(__fdiv_rn(p[1], dlf));
    int cz = (int)floorf(__fdiv_rn(p[2], dlf));
    cx = min(max(cx, 0), G - 1);
    cy = min(max(cy, 0), G - 1);
    cz = min(max(cz, 0), G - 1);
    vid[(size_t)b * NN + i] = (cx * G + cy) * G + cz;  // lexicographic == ref key order
}

// deterministic per-voxel accumulation, wave-per-voxel (bit-exact ordering)
__global__ __launch_bounds__(256) void vscan_kernel(
    const float* __restrict__ pts, const int* __restrict__ vid,
    const int* __restrict__ len_ptr, int len_const,
    float* __restrict__ vsum, int* __restrict__ vcnt, int G3) {
    int b = blockIdx.y;
    int t = threadIdx.x;
    int w = t >> 6, lane = t & 63;
    int v = blockIdx.x * 4 + w;          // one wave per voxel
    if (v >= G3) return;                 // wave-uniform, no syncthreads in kernel
    int len = len_ptr ? len_ptr[b] : len_const;
    const int* vb = vid + (size_t)b * NN;
    const float* pb = pts + (size_t)b * NN * 3;
    float sx = 0.f, sy = 0.f, sz = 0.f;
    int c = 0;
    for (int base = 0; base < len; base += 64) {
        int i = base + lane;
        int myv = (i < len) ? vb[i] : -1;
        ull m = __ballot(myv == v);
        while (m) {                       // m wave-uniform; body runs on all lanes
            int bit = __ffsll(m) - 1;
            m &= m - 1;                   // clear lowest set bit -> ascending order
            int idx = base + bit;
            sx = __fadd_rn(sx, pb[idx * 3]);
            sy = __fadd_rn(sy, pb[idx * 3 + 1]);
            sz = __fadd_rn(sz, pb[idx * 3 + 2]);
            ++c;
        }
    }
    if (lane == 0) {
        size_t o = (size_t)b * G3 + v;
        vsum[o * 3]     = sx;
        vsum[o * 3 + 1] = sy;
        vsum[o * 3 + 2] = sz;
        vcnt[o] = c;
    }
}

// compact occupied voxels in id (== key) order -> padded means + length.
// MEAN = sum * f32(1/cnt) (reciprocal-multiply — matches the np reference
// EXACTLY; verified bit-exact in R14. DO NOT change to true division.)
__global__ __launch_bounds__(1024) void compact_kernel(
    const float* __restrict__ vsum, const int* __restrict__ vcnt, int G3,
    float* __restrict__ out_pts, int* __restrict__ len_dev,
    float* __restrict__ len_out_f) {
    __shared__ int wsum[16];
    int b = blockIdx.x;
    int t = threadIdx.x;
    int per = (G3 + 1023) >> 10;
    int start = t * per;
    int end = min(start + per, G3);
    if (start > G3) start = G3;
    int c = 0;
    for (int v = start; v < end; ++v) c += (vcnt[(size_t)b * G3 + v] > 0);
    int lane = t & 63, wid = t >> 6;
    int inc = c;
    for (int d = 1; d < 64; d <<= 1) {
        int u = __shfl_up(inc, d);
        if (lane >= d) inc += u;
    }
    if (lane == 63) wsum[wid] = inc;
    __syncthreads();
    if (t < 16) {
        int wv = wsum[t];
        for (int d = 1; d < 16; d <<= 1) {
            int u = __shfl_up(wv, d);
            if (t >= d) wv += u;
        }
        wsum[t] = wv;
    }
    __syncthreads();
    int excl = inc - c + (wid ? wsum[wid - 1] : 0);
    int total = wsum[15];
    int off = excl;
    for (int v = start; v < end; ++v) {
        int cn = vcnt[(size_t)b * G3 + v];
        if (cn > 0) {
            float rinv = __frcp_rn((float)cn);
            const float* sp = vsum + ((size_t)b * G3 + v) * 3;
            float* op = out_pts + ((size_t)b * NN + off) * 3;
            op[0] = __fmul_rn(sp[0], rinv);
            op[1] = __fmul_rn(sp[1], rinv);
            op[2] = __fmul_rn(sp[2], rinv);
            ++off;
        }
    }
    for (int r = total + t; r < NN; r += 1024) {
        float* op = out_pts + ((size_t)b * NN + r) * 3;
        op[0] = 0.f; op[1] = 0.f; op[2] = 0.f;
    }
    if (t == 0) {
        len_dev[b] = total;
        len_out_f[b] = (float)total;
    }
}

extern "C" void kernel_launch(void* const* d_in, const int* in_sizes, int n_in,
                              void* d_out, int out_size, void* d_ws, size_t ws_size,
                              hipStream_t stream) {
    const float* pts = (const float*)d_in[0];
    float* dout = (float*)d_out;
    const size_t PN = (size_t)BB * NN * 3;     // 49152
    const size_t IN = (size_t)BB * NN * KNN;   // 655360
    float* out_points = dout;
    float* out_neigh  = dout + 3 * PN;
    float* out_pool   = out_neigh + 3 * IN;
    float* out_up     = out_pool + 3 * IN;
    float* out_len    = out_up + 3 * IN;
    float* pts1 = out_points + PN;       // layer-1 points live directly in d_out
    float* pts2 = out_points + 2 * PN;

    // workspace layout (everything written before read -> no memset needed)
    char*  wsb   = (char*)d_ws;
    int*   vid0  = (int*)wsb;                                // BB*NN
    int*   vid1  = vid0 + (size_t)BB * NN;                   // BB*NN
    float* vsum0 = (float*)(vid1 + (size_t)BB * NN);         // BB*G0_3*3
    int*   vcnt0 = (int*)(vsum0 + (size_t)BB * G0_3 * 3);    // BB*G0_3
    float* vsum1 = (float*)(vcnt0 + (size_t)BB * G0_3);      // BB*G1_3*3
    int*   vcnt1 = (int*)(vsum1 + (size_t)BB * G1_3 * 3);    // BB*G1_3
    int*   len1  = vcnt1 + (size_t)BB * G1_3;
    int*   len2  = len1 + BB;
    size_t fixed_end = (size_t)((char*)(len2 + BB) - wsb);
    size_t bqoff = (fixed_end + 255) & ~(size_t)255;
    const size_t NE  = (size_t)BB * QCH * KNN * SPLIT * 64;  // 5.24M entries
    u32* wsH = (u32*)(wsb + bqoff);                          // 21.0 MB
    u16* wsL = (u16*)(wsb + bqoff + NE * sizeof(u32));       // 10.5 MB
    bool twopass = ws_size >= bqoff + NE * 6;

    // mirror Python double-precision scalar arithmetic, then narrow to f32
    double r_normal = 0.03 * 2.5;                 // 0.075
    double r0 = r_normal;
    double dl0 = 2.0 * r_normal / 2.5;            // 0.06
    float r2_0   = (float)(r0 * r0);
    float r2_up0 = (float)((2.0 * r0) * (2.0 * r0));
    float dlf0   = (float)dl0;
    r_normal *= 2.0;                              // 0.15
    double r1 = r_normal;
    double dl1 = 2.0 * r_normal / 2.5;            // 0.12
    float r2_1   = (float)(r1 * r1);
    float r2_up1 = (float)((2.0 * r1) * (2.0 * r1));
    float dlf1   = (float)dl1;
    r_normal *= 2.0;                              // 0.3
    float r2_2 = (float)(r_normal * r_normal);

    dim3 bqgrid(NN / QB, BB);
    dim3 vxgrid(NN / 256, BB);
    dim3 vsgrid0((G0_3 + 3) / 4, BB);   // one wave (of 4 per block) per voxel
    dim3 vsgrid1((G1_3 + 3) / 4, BB);
    dim3 mgrid(NN / 256, BB);
    int  pgrid = BB * QCH * SPLIT / 4;  // 512 blocks x 4 waves

    auto BQ = [&](const float* qp, const float* sp,
                  const int* qlp, int qlc, const int* slp, int slc,
                  float* o, float rr2) {
        if (twopass) {
            bq_part<<<pgrid, 256, 0, stream>>>(qp, sp, qlp, qlc, slp, slc, wsH, wsL, rr2);
            bq_merge<<<mgrid, 256, 0, stream>>>(wsH, wsL, qlp, qlc, o);
        } else {
            bq_kernel<<<bqgrid, BQT, 0, stream>>>(qp, sp, qlp, qlc, slp, slc, o, rr2);
        }
    };

    prep_kernel<<<(int)((IN + 255) / 256), 256, 0, stream>>>(pts, dout);
    // layer 0
    BQ(pts, pts, nullptr, NN, nullptr, NN, out_neigh + 0 * IN, r2_0);
    vid_kernel<<<vxgrid, 256, 0, stream>>>(pts, nullptr, NN, vid0, dlf0, G0);
    vscan_kernel<<<vsgrid0, 256, 0, stream>>>(pts, vid0, nullptr, NN, vsum0, vcnt0, G0_3);
    compact_kernel<<<BB, 1024, 0, stream>>>(vsum0, vcnt0, G0_3, pts1, len1, out_len + 2);
    BQ(pts1, pts, len1, 0, nullptr, NN, out_pool + 0 * IN, r2_0);
    BQ(pts, pts1, nullptr, NN, len1, 0, out_up + 0 * IN, r2_up0);
    // layer 1
    vid_kernel<<<vxgrid, 256, 0, stream>>>(pts1, len1, 0, vid1, dlf1, G1);
    vscan_kernel<<<vsgrid1, 256, 0, stream>>>(pts1, vid1, len1, 0, vsum1, vcnt1, G1_3);
    compact_kernel<<<BB, 1024, 0, stream>>>(vsum1, vcnt1, G1_3, pts2, len2, out_len + 4);
    BQ(pts1, pts1, len1, 0, len1, 0, out_neigh + 1 * IN, r2_1);
    BQ(pts2, pts1, len2, 0, len1, 0, out_pool + 1 * IN, r2_1);
    BQ(pts1, pts2, len1, 0, len2, 0, out_up + 1 * IN, r2_up1);
    // layer 2
    BQ(pts2, pts2, len2, 0, len2, 0, out_neigh + 2 * IN, r2_2);
}

// Round 6
// 1094.434 us; speedup vs baseline: 1.6184x; 1.6184x over previous
//
#include <hip/hip_runtime.h>

// ---- static config (mirrors reference) ----
#define BB   2
#define NN   8192
#define KNN  40
#define SENT 8192
#define G0   17          // ceil coords for dl=0.06, pts in [0,1)
#define G1   9           // for dl=0.12
#define G0_3 (G0*G0*G0)  // 4913
#define G1_3 (G1*G1*G1)  // 729

#define QB    64         // queries per block (one per lane)
#define NWAVE 8          // waves per block = support-split factor
#define BQT   512        // threads per block

typedef unsigned long long ull;
typedef unsigned int       u32;
typedef unsigned short     u16;

// d2 exactly as numpy: (dx*dx + dy*dy) + dz*dz, no FMA contraction
__device__ __forceinline__ float sqdist(float qx, float qy, float qz,
                                        float sx, float sy, float sz) {
    float dx = __fsub_rn(qx, sx);
    float dy = __fsub_rn(qy, sy);
    float dz = __fsub_rn(qz, sz);
    return __fadd_rn(__fadd_rn(__fmul_rn(dx, dx), __fmul_rn(dy, dy)),
                     __fmul_rn(dz, dz));
}

// uniform-lane broadcast via readlane (SALU path, no DS-pipe lgkmcnt stall).
// u MUST be wave-uniform (it is: the loop counter).  Value-flow identical to
// __shfl(x, u) -> bit-identical results.
__device__ __forceinline__ float bcast(float x, int u) {
    return __int_as_float(__builtin_amdgcn_readlane(__float_as_int(x), u));
}

// prep: copy pts -> out_points[0], fill layer-2 pool/up with SENTINEL, len[0]
__global__ void prep_kernel(const float* __restrict__ pts, float* __restrict__ dout) {
    const size_t PN = (size_t)BB * NN * 3;
    const size_t IN = (size_t)BB * NN * KNN;
    float* out_points0 = dout;
    float* out_pool2   = dout + 3 * PN + 3 * IN + 2 * IN;
    float* out_up2     = dout + 3 * PN + 6 * IN + 2 * IN;
    float* out_len     = dout + 3 * PN + 9 * IN;
    int i = blockIdx.x * 256 + threadIdx.x;
    if (i < (int)PN) out_points0[i] = pts[i];
    if (i < (int)IN) {
        out_pool2[i] = (float)SENT;
        out_up2[i]   = (float)SENT;
    }
    if (i == 0) { out_len[0] = (float)NN; out_len[1] = (float)NN; }
}

// ---- 40 named register slots for the sorted top-40 key list ----
#define FORALL_K(M) \
    M(0,k00) M(1,k01) M(2,k02) M(3,k03) M(4,k04) M(5,k05) M(6,k06) M(7,k07) \
    M(8,k08) M(9,k09) M(10,k10) M(11,k11) M(12,k12) M(13,k13) M(14,k14) M(15,k15) \
    M(16,k16) M(17,k17) M(18,k18) M(19,k19) M(20,k20) M(21,k21) M(22,k22) M(23,k23) \
    M(24,k24) M(25,k25) M(26,k26) M(27,k27) M(28,k28) M(29,k29) M(30,k30) M(31,k31) \
    M(32,k32) M(33,k33) M(34,k34) M(35,k35) M(36,k36) M(37,k37) M(38,k38) M(39,k39)

// radius ball query, 8-way support-split, register-resident top-40.
//
// Key = (f32_bits(d2) << 13) | idx  (d2 >= 0 so float bits are order-monotone;
// idx < 8192 fits 13 bits).  u64 key compare == (d2, idx) lexicographic order,
// exactly the reference's stable top_k tie-break (lower idx first).
// Empty slot = all-ones key (INITK); merge maps it to SENT.
// Selection of the 40 smallest keys is candidate-ORDER-INDEPENDENT, so the
// support partition across waves is semantics-free.
//
// R6 scan: per 64-candidate block, lane i loads point (base+i) with coalesced
// loads (vmcnt wait once per 64 candidates); the inner loop broadcasts
// candidate u's coords via READLANE (SALU, no lgkmcnt stall — R4/R5's __shfl
// compiled to ds_bpermute and stalled ~100cyc/candidate; R2/R3 stalled on a
// dependent global load per candidate.  All three measured identical totals:
// the serial per-candidate latency stall IS the bottleneck).
__global__ __launch_bounds__(BQT, 2) void bq_kernel(
    const float* __restrict__ qpts, const float* __restrict__ spts,
    const int* __restrict__ qlen_ptr, int qlen_const,
    const int* __restrict__ slen_ptr, int slen_const,
    float* __restrict__ out, float r2) {
    __shared__ u32 khl[NWAVE][KNN][QB];   // key >> 13 (== d2 bits)    80 KiB
    __shared__ u16 kll[NWAVE][KNN][QB];   // key & 0x1FFF (== idx)     40 KiB
    const ull INITK = ~0ull;

    int t = threadIdx.x;
    int w = __builtin_amdgcn_readfirstlane(t >> 6);   // wave id, force SGPR
    int lane = t & 63;
    int b = blockIdx.y;
    int qbase = blockIdx.x * QB;
    int qi = qbase + lane;
    int qlen = qlen_ptr ? qlen_ptr[b] : qlen_const;
    int slen = slen_ptr ? slen_ptr[b] : slen_const;

#define DECL_K(I,K) ull K = INITK;
    FORALL_K(DECL_K)
#undef DECL_K

#define SW1(K) { bool sw_ = ck < K; ull t_ = sw_ ? K : ck; K = sw_ ? ck : K; ck = t_; }
    if (qbase < qlen) {          // block-uniform
        const float* qp = qpts + ((size_t)b * NN + qi) * 3;
        float qx = qp[0], qy = qp[1], qz = qp[2];
        if (qi >= qlen) { qx = 1.0e30f; qy = 1.0e30f; qz = 1.0e30f; } // d2=inf -> never accepts
        int j0 = (slen * w) >> 3;
        int j1 = (slen * (w + 1)) >> 3;
        const float* sp = spts + (size_t)b * NN * 3;
        for (int base = j0; base < j1; base += 64) {
            int nj = min(64, j1 - base);
            // coalesced block load: lane i holds support point (base+i)
            float px = 0.f, py = 0.f, pz = 0.f;
            {
                int jj = base + lane;
                if (lane < nj) {
                    px = sp[jj * 3];
                    py = sp[jj * 3 + 1];
                    pz = sp[jj * 3 + 2];
                }
            }
#pragma unroll 2
            for (int u = 0; u < nj; ++u) {
                float sx = bcast(px, u);         // SALU broadcast, no stall
                float sy = bcast(py, u);
                float sz = bcast(pz, u);
                float d2 = sqdist(qx, qy, qz, sx, sy, sz);
                if (d2 <= r2) {                  // ref keeps d2 <= r^2
                    ull ck = (((ull)__float_as_uint(d2)) << 13) | (ull)(u32)(base + u);
                    if (ck < k39) {              // prune: not better than 40th -> skip
                        // carry-swap insertion; wave-uniform early exits every 8
                        // (inserting INITK is a no-op, so skipping is exact)
                        SW1(k00) SW1(k01) SW1(k02) SW1(k03) SW1(k04) SW1(k05) SW1(k06) SW1(k07)
                        if (__any(ck != INITK)) {
                            SW1(k08) SW1(k09) SW1(k10) SW1(k11) SW1(k12) SW1(k13) SW1(k14) SW1(k15)
                            if (__any(ck != INITK)) {
                                SW1(k16) SW1(k17) SW1(k18) SW1(k19) SW1(k20) SW1(k21) SW1(k22) SW1(k23)
                                if (__any(ck != INITK)) {
                                    SW1(k24) SW1(k25) SW1(k26) SW1(k27) SW1(k28) SW1(k29) SW1(k30) SW1(k31)
                                    if (__any(ck != INITK)) {
                                        SW1(k32) SW1(k33) SW1(k34) SW1(k35) SW1(k36) SW1(k37) SW1(k38) SW1(k39)
                                    }
                                }
                            }
                        }
                    }
                }
            }
        }
    }
#undef SW1
    // dump partial lists (always, so inactive blocks still publish INITK)
#define DUMP_K(I,K) khl[w][I][lane] = (u32)(K >> 13); kll[w][I][lane] = (u16)(K & 0x1FFFu);
    FORALL_K(DUMP_K)
#undef DUMP_K
    __syncthreads();
    // stable 8-way merge by key: wave 0, lane = query.
    // Pointers sum to k <= 39 before each pick -> every p[c] <= 39, no OOB.
    if (w == 0) {
        float* op = out + ((size_t)b * NN + qi) * KNN;
        int p[NWAVE];
#pragma unroll
        for (int c = 0; c < NWAVE; ++c) p[c] = 0;
        for (int k = 0; k < KNN; ++k) {
            ull bk = ~0ull; int bw = 0;
#pragma unroll
            for (int c = 0; c < NWAVE; ++c) {
                ull kk = (((ull)khl[c][p[c]][lane]) << 13) | (ull)kll[c][p[c]][lane];
                if (kk < bk) { bk = kk; bw = c; }    // reconstructed keys < 2^45-1 == INIT
            }
#pragma unroll
            for (int c = 0; c < NWAVE; ++c) p[c] += (bw == c);
            op[k] = ((u32)(bk >> 13) == 0xFFFFFFFFu) ? (float)SENT
                                                     : (float)(int)(bk & 0x1FFFu);
        }
    }
}

// per-point voxel id (f32 division, f32 dl)
__global__ void vid_kernel(const float* __restrict__ pts,
                           const int* __restrict__ len_ptr, int len_const,
                           int* __restrict__ vid, float dlf, int G) {
    int b = blockIdx.y;
    int i = blockIdx.x * 256 + threadIdx.x;
    int len = len_ptr ? len_ptr[b] : len_const;
    if (i >= len) return;
    const float* p = pts + ((size_t)b * NN + i) * 3;
    int cx = (int)floorf(__fdiv_rn(p[0], dlf));
    int cy = (int)floorf(__fdiv_rn(p[1], dlf));
    int cz = (int)floorf(__fdiv_rn(p[2], dlf));
    cx = min(max(cx, 0), G - 1);
    cy = min(max(cy, 0), G - 1);
    cz = min(max(cz, 0), G - 1);
    vid[(size_t)b * NN + i] = (cx * G + cy) * G + cz;  // lexicographic == ref key order
}

// deterministic per-voxel accumulation, wave-per-voxel (bit-exact ordering)
__global__ __launch_bounds__(256) void vscan_kernel(
    const float* __restrict__ pts, const int* __restrict__ vid,
    const int* __restrict__ len_ptr, int len_const,
    float* __restrict__ vsum, int* __restrict__ vcnt, int G3) {
    int b = blockIdx.y;
    int t = threadIdx.x;
    int w = t >> 6, lane = t & 63;
    int v = blockIdx.x * 4 + w;          // one wave per voxel
    if (v >= G3) return;                 // wave-uniform, no syncthreads in kernel
    int len = len_ptr ? len_ptr[b] : len_const;
    const int* vb = vid + (size_t)b * NN;
    const float* pb = pts + (size_t)b * NN * 3;
    float sx = 0.f, sy = 0.f, sz = 0.f;
    int c = 0;
    for (int base = 0; base < len; base += 64) {
        int i = base + lane;
        int myv = (i < len) ? vb[i] : -1;
        ull m = __ballot(myv == v);
        while (m) {                       // m wave-uniform; body runs on all lanes
            int bit = __ffsll(m) - 1;
            m &= m - 1;                   // clear lowest set bit -> ascending order
            int idx = base + bit;
            sx = __fadd_rn(sx, pb[idx * 3]);
            sy = __fadd_rn(sy, pb[idx * 3 + 1]);
            sz = __fadd_rn(sz, pb[idx * 3 + 2]);
            ++c;
        }
    }
    if (lane == 0) {
        size_t o = (size_t)b * G3 + v;
        vsum[o * 3]     = sx;
        vsum[o * 3 + 1] = sy;
        vsum[o * 3 + 2] = sz;
        vcnt[o] = c;
    }
}

// compact occupied voxels in id (== key) order -> padded means + length.
// MEAN = sum * f32(1/cnt) (reciprocal-multiply — matches the np reference
// EXACTLY; verified bit-exact in R14. DO NOT change to true division.)
__global__ __launch_bounds__(1024) void compact_kernel(
    const float* __restrict__ vsum, const int* __restrict__ vcnt, int G3,
    float* __restrict__ out_pts, int* __restrict__ len_dev,
    float* __restrict__ len_out_f) {
    __shared__ int wsum[16];
    int b = blockIdx.x;
    int t = threadIdx.x;
    int per = (G3 + 1023) >> 10;
    int start = t * per;
    int end = min(start + per, G3);
    if (start > G3) start = G3;
    int c = 0;
    for (int v = start; v < end; ++v) c += (vcnt[(size_t)b * G3 + v] > 0);
    int lane = t & 63, wid = t >> 6;
    int inc = c;
    for (int d = 1; d < 64; d <<= 1) {
        int u = __shfl_up(inc, d);
        if (lane >= d) inc += u;
    }
    if (lane == 63) wsum[wid] = inc;
    __syncthreads();
    if (t < 16) {
        int wv = wsum[t];
        for (int d = 1; d < 16; d <<= 1) {
            int u = __shfl_up(wv, d);
            if (t >= d) wv += u;
        }
        wsum[t] = wv;
    }
    __syncthreads();
    int excl = inc - c + (wid ? wsum[wid - 1] : 0);
    int total = wsum[15];
    int off = excl;
    for (int v = start; v < end; ++v) {
        int cn = vcnt[(size_t)b * G3 + v];
        if (cn > 0) {
            float rinv = __frcp_rn((float)cn);
            const float* sp = vsum + ((size_t)b * G3 + v) * 3;
            float* op = out_pts + ((size_t)b * NN + off) * 3;
            op[0] = __fmul_rn(sp[0], rinv);
            op[1] = __fmul_rn(sp[1], rinv);
            op[2] = __fmul_rn(sp[2], rinv);
            ++off;
        }
    }
    for (int r = total + t; r < NN; r += 1024) {
        float* op = out_pts + ((size_t)b * NN + r) * 3;
        op[0] = 0.f; op[1] = 0.f; op[2] = 0.f;
    }
    if (t == 0) {
        len_dev[b] = total;
        len_out_f[b] = (float)total;
    }
}

extern "C" void kernel_launch(void* const* d_in, const int* in_sizes, int n_in,
                              void* d_out, int out_size, void* d_ws, size_t ws_size,
                              hipStream_t stream) {
    const float* pts = (const float*)d_in[0];
    float* dout = (float*)d_out;
    const size_t PN = (size_t)BB * NN * 3;     // 49152
    const size_t IN = (size_t)BB * NN * KNN;   // 655360
    float* out_points = dout;
    float* out_neigh  = dout + 3 * PN;
    float* out_pool   = out_neigh + 3 * IN;
    float* out_up     = out_pool + 3 * IN;
    float* out_len    = out_up + 3 * IN;
    float* pts1 = out_points + PN;       // layer-1 points live directly in d_out
    float* pts2 = out_points + 2 * PN;

    // workspace layout (everything written before read -> no memset needed)
    int*   vid0  = (int*)d_ws;                               // BB*NN
    int*   vid1  = vid0 + (size_t)BB * NN;                   // BB*NN
    float* vsum0 = (float*)(vid1 + (size_t)BB * NN);         // BB*G0_3*3
    int*   vcnt0 = (int*)(vsum0 + (size_t)BB * G0_3 * 3);    // BB*G0_3
    float* vsum1 = (float*)(vcnt0 + (size_t)BB * G0_3);      // BB*G1_3*3
    int*   vcnt1 = (int*)(vsum1 + (size_t)BB * G1_3 * 3);    // BB*G1_3
    int*   len1  = vcnt1 + (size_t)BB * G1_3;
    int*   len2  = len1 + BB;

    // mirror Python double-precision scalar arithmetic, then narrow to f32
    double r_normal = 0.03 * 2.5;                 // 0.075
    double r0 = r_normal;
    double dl0 = 2.0 * r_normal / 2.5;            // 0.06
    float r2_0   = (float)(r0 * r0);
    float r2_up0 = (float)((2.0 * r0) * (2.0 * r0));
    float dlf0   = (float)dl0;
    r_normal *= 2.0;                              // 0.15
    double r1 = r_normal;
    double dl1 = 2.0 * r_normal / 2.5;            // 0.12
    float r2_1   = (float)(r1 * r1);
    float r2_up1 = (float)((2.0 * r1) * (2.0 * r1));
    float dlf1   = (float)dl1;
    r_normal *= 2.0;                              // 0.3
    float r2_2 = (float)(r_normal * r_normal);

    dim3 bqgrid(NN / QB, BB);
    dim3 vxgrid(NN / 256, BB);
    dim3 vsgrid0((G0_3 + 3) / 4, BB);   // one wave (of 4 per block) per voxel
    dim3 vsgrid1((G1_3 + 3) / 4, BB);

    prep_kernel<<<(int)((IN + 255) / 256), 256, 0, stream>>>(pts, dout);
    // layer 0
    bq_kernel<<<bqgrid, BQT, 0, stream>>>(pts, pts, nullptr, NN, nullptr, NN,
                                          out_neigh + 0 * IN, r2_0);
    vid_kernel<<<vxgrid, 256, 0, stream>>>(pts, nullptr, NN, vid0, dlf0, G0);
    vscan_kernel<<<vsgrid0, 256, 0, stream>>>(pts, vid0, nullptr, NN, vsum0, vcnt0, G0_3);
    compact_kernel<<<BB, 1024, 0, stream>>>(vsum0, vcnt0, G0_3, pts1, len1, out_len + 2);
    bq_kernel<<<bqgrid, BQT, 0, stream>>>(pts1, pts, len1, 0, nullptr, NN,
                                          out_pool + 0 * IN, r2_0);
    bq_kernel<<<bqgrid, BQT, 0, stream>>>(pts, pts1, nullptr, NN, len1, 0,
                                          out_up + 0 * IN, r2_up0);
    // layer 1
    vid_kernel<<<vxgrid, 256, 0, stream>>>(pts1, len1, 0, vid1, dlf1, G1);
    vscan_kernel<<<vsgrid1, 256, 0, stream>>>(pts1, vid1, len1, 0, vsum1, vcnt1, G1_3);
    compact_kernel<<<BB, 1024, 0, stream>>>(vsum1, vcnt1, G1_3, pts2, len2, out_len + 4);
    bq_kernel<<<bqgrid, BQT, 0, stream>>>(pts1, pts1, len1, 0, len1, 0,
                                          out_neigh + 1 * IN, r2_1);
    bq_kernel<<<bqgrid, BQT, 0, stream>>>(pts2, pts1, len2, 0, len1, 0,
                                          out_pool + 1 * IN, r2_1);
    bq_kernel<<<bqgrid, BQT, 0, stream>>>(pts1, pts2, len1, 0, len2, 0,
                                          out_up + 1 * IN, r2_up1);
    // layer 2
    bq_kernel<<<bqgrid, BQT, 0, stream>>>(pts2, pts2, len2, 0, len2, 0,
                                          out_neigh + 2 * IN, r2_2);
}